// Round 4
// baseline (733.126 us; speedup 1.0000x reference)
//
#include <hip/hip_runtime.h>

typedef unsigned short u16;
typedef _Float16 f16;
typedef __attribute__((ext_vector_type(8))) short v8s;
typedef __attribute__((ext_vector_type(4))) short v4s;
typedef __attribute__((ext_vector_type(8))) f16   v8h;
typedef __attribute__((ext_vector_type(4))) float v4f;
typedef __attribute__((ext_vector_type(2))) unsigned v2u;

#define NB   8
#define NC   256
#define DQK  32
#define NPIX 4096

__device__ __forceinline__ u16 f2bf(float f) {
  unsigned u = __builtin_bit_cast(unsigned, f);
  u += 0x7FFFu + ((u >> 16) & 1u);   // RNE
  return (u16)(u >> 16);
}
__device__ __forceinline__ u16 f2h(float f) {
  return __builtin_bit_cast(u16, (f16)f);   // v_cvt_f16_f32, RNE
}
__device__ __forceinline__ unsigned pk_bf16(float a, float b) {  // lo=a, hi=b
#if defined(__gfx950__)
  unsigned r;
  asm("v_cvt_pk_bf16_f32 %0, %1, %2" : "=v"(r) : "v"(a), "v"(b));
  return r;
#else
  return (unsigned)f2bf(a) | ((unsigned)f2bf(b) << 16);
#endif
}

// ---- W -> fp16 ([o][c] row-major, elementwise) ----
__global__ __launch_bounds__(256)
void convert_w(const float* __restrict__ Wq, const float* __restrict__ Wk,
               const float* __restrict__ Wv,
               u16* __restrict__ Whq, u16* __restrict__ Whk, u16* __restrict__ Whv) {
  int i = blockIdx.x * 256 + threadIdx.x;   // 0..81919
  if (i < 8192)       Whq[i]         = f2h(Wq[i]);
  else if (i < 16384) Whk[i - 8192]  = f2h(Wk[i - 8192]);
  else                Whv[i - 16384] = f2h(Wv[i - 16384]);
}

// ---- Projections (Q,K,V) with fused in-LDS transpose of x/y (no global xpose) ----
// Block: 4 waves, 64 pixels. Phase 1: stage fp32 [c][n] tile -> fp16 [n][c] in LDS
// (b32 pair-packed writes, 2-way bank aliasing only). Phase 2: MFMA, frags from LDS.
__global__ __launch_bounds__(256)
void proj_mfma(const float* __restrict__ x, const float* __restrict__ y,
               const u16* __restrict__ Whq, const float* __restrict__ bq,
               const u16* __restrict__ Whk, const float* __restrict__ bk,
               const u16* __restrict__ Whv, const float* __restrict__ bv,
               u16* __restrict__ Qb, u16* __restrict__ Kb, u16* __restrict__ Vt) {
  __shared__ __attribute__((aligned(16))) unsigned Ts[64][130];   // 33280 B
  const int tid = threadIdx.x, w = tid >> 6, lane = tid & 63;
  const int lr = lane & 15, quad = lane >> 4;
  const int b  = blockIdx.x & 7;                 // XCD-affine batch
  const int n0 = (blockIdx.x >> 3) * 64;
  const int g  = tid & 3, nl = tid >> 2;         // lane-group / pixel row in tile
  const size_t base_b = (size_t)b << 20;

  v8h xb[8], yb[8];
  // ---- stage + fragment x ----
  {
    const float* s = x + base_b + n0 + nl;
#pragma unroll 4
    for (int i = 0; i < 32; ++i) {
      int c = 2 * g + 8 * i;
      float f0 = s[(size_t)c << 12];
      float f1 = s[(size_t)(c + 1) << 12];
      Ts[nl][g + 4 * i] = (unsigned)f2h(f0) | ((unsigned)f2h(f1) << 16);
    }
    __syncthreads();
    const u16* row = (const u16*)&Ts[w * 16 + lr][0];
#pragma unroll
    for (int t = 0; t < 8; ++t) xb[t] = *(const v8h*)(row + quad * 8 + 32 * t);
    __syncthreads();
  }
  // ---- stage + fragment y ----
  {
    const float* s = y + base_b + n0 + nl;
#pragma unroll 4
    for (int i = 0; i < 32; ++i) {
      int c = 2 * g + 8 * i;
      float f0 = s[(size_t)c << 12];
      float f1 = s[(size_t)(c + 1) << 12];
      Ts[nl][g + 4 * i] = (unsigned)f2h(f0) | ((unsigned)f2h(f1) << 16);
    }
    __syncthreads();
    const u16* row = (const u16*)&Ts[w * 16 + lr][0];
#pragma unroll
    for (int t = 0; t < 8; ++t) yb[t] = *(const v8h*)(row + quad * 8 + 32 * t);
  }

  const int n = n0 + w * 16 + lr;
  const size_t bn = ((size_t)b << 12) + n;

  // Q and K (2 o-tiles each), fp16 out, pixel-major [n][32]
#pragma unroll
  for (int ot = 0; ot < 2; ++ot) {
    v4f aq = {0.f, 0.f, 0.f, 0.f}, ak = {0.f, 0.f, 0.f, 0.f};
#pragma unroll
    for (int t = 0; t < 8; ++t) {
      v8h wq = *(const v8h*)(Whq + (ot * 16 + lr) * 256 + quad * 8 + 32 * t);
      v8h wk = *(const v8h*)(Whk + (ot * 16 + lr) * 256 + quad * 8 + 32 * t);
      aq = __builtin_amdgcn_mfma_f32_16x16x32_f16(wq, xb[t], aq, 0, 0, 0);
      ak = __builtin_amdgcn_mfma_f32_16x16x32_f16(wk, yb[t], ak, 0, 0, 0);
    }
    v4f bqv = *(const v4f*)(bq + ot * 16 + quad * 4);
    v4f bkv = *(const v4f*)(bk + ot * 16 + quad * 4);
    v4s q4, k4;
#pragma unroll
    for (int r = 0; r < 4; ++r) {
      q4[r] = (short)f2h(aq[r] + bqv[r]);
      k4[r] = (short)f2h(ak[r] + bkv[r]);
    }
    *(v4s*)(Qb + bn * DQK + ot * 16 + quad * 4) = q4;
    *(v4s*)(Kb + bn * DQK + ot * 16 + quad * 4) = k4;
  }

  // V (16 o-tiles) -> channel-major bf16 [b][o][n]
  for (int vt = 0; vt < 16; ++vt) {
    v4f av = {0.f, 0.f, 0.f, 0.f};
#pragma unroll
    for (int t = 0; t < 8; ++t) {
      v8h wv = *(const v8h*)(Whv + (vt * 16 + lr) * 256 + quad * 8 + 32 * t);
      av = __builtin_amdgcn_mfma_f32_16x16x32_f16(wv, yb[t], av, 0, 0, 0);
    }
#pragma unroll
    for (int r = 0; r < 4; ++r) {
      int o = vt * 16 + quad * 4 + r;
      Vt[(((size_t)b << 8) + o) * NPIX + n] = f2bf(av[r] + bv[o]);
    }
  }
}

// ---- Fused attention, 8 waves/block, in-block kv-split (waves 0-3: half 0, 4-7: half 1) ----
// S^T via operand-swapped fp16 MFMA (lane holds 4 consecutive kv -> pk_bf16 + ds_write_b64).
// Fixed-shift softmax: partials combine by plain addition (O^T and l) in LDS at the end.
__global__ __launch_bounds__(512, 4)
void attn_kernel(const u16* __restrict__ Qb, const u16* __restrict__ Kb,
                 const u16* __restrict__ Vt, float* __restrict__ out) {
  __shared__ __attribute__((aligned(16))) u16 Ps[2][2][4][16 * 72];  // 36864 B
  __shared__ float Ls[2][64];

  const int tid  = threadIdx.x;
  const int w    = tid >> 6;
  const int lane = tid & 63;
  const int lr   = lane & 15;
  const int quad = lane >> 4;
  const int h    = w >> 2;       // kv half
  const int ws   = w & 3;        // q-subtile for S, 64-ch slice for PV

  const int b  = blockIdx.x & 7;
  const int q0 = (blockIdx.x >> 3) << 6;
  const int kvbase = h * 2048;

  const u16* Qp = Qb + ((size_t)b * NPIX + q0) * DQK;
  const u16* Kp = Kb + ((size_t)b * NPIX + kvbase) * DQK;
  const u16* Vp = Vt + (size_t)b * NC * NPIX + (size_t)(ws * 64 + lr) * NPIX + kvbase;

  v8h q_frag = *(const v8h*)(Qp + (ws * 16 + lr) * DQK + quad * 8);

  v8s ones;
#pragma unroll
  for (int j = 0; j < 8; ++j) ones[j] = (short)0x3F80;  // bf16 1.0

  v4f acc[4][4];
#pragma unroll
  for (int qt = 0; qt < 4; ++qt)
#pragma unroll
    for (int ct = 0; ct < 4; ++ct) acc[qt][ct] = (v4f){0.f, 0.f, 0.f, 0.f};
  v4f lacc = (v4f){0.f, 0.f, 0.f, 0.f};

  // prologue loads (it = 0)
  v8h kf[4];
  v8s vf[4][2];
#pragma unroll
  for (int nt = 0; nt < 4; ++nt)
    kf[nt] = *(const v8h*)(Kp + (size_t)(nt * 16 + lr) * DQK + quad * 8);
#pragma unroll
  for (int ct = 0; ct < 4; ++ct) {
    const u16* vs = Vp + (size_t)ct * 16 * NPIX + quad * 8;
    vf[ct][0] = *(const v8s*)(vs);
    vf[ct][1] = *(const v8s*)(vs + 32);
  }

#pragma unroll 2
  for (int it = 0; it < 32; ++it) {
    const int buf = it & 1;
    // S^T = K Q^T : row = kv (quad*4+r), col = q (lr)
    v4f s[4];
#pragma unroll
    for (int nt = 0; nt < 4; ++nt)
      s[nt] = __builtin_amdgcn_mfma_f32_16x16x32_f16(kf[nt], q_frag,
                                                     (v4f){0.f, 0.f, 0.f, 0.f}, 0, 0, 0);
    // prefetch next iteration's K/V
    v8h kn[4];
    v8s vn[4][2];
    if (it < 31) {
      const int kvn = (it + 1) * 64;
#pragma unroll
      for (int nt = 0; nt < 4; ++nt)
        kn[nt] = *(const v8h*)(Kp + (size_t)(kvn + nt * 16 + lr) * DQK + quad * 8);
#pragma unroll
      for (int ct = 0; ct < 4; ++ct) {
        const u16* vs = Vp + (size_t)ct * 16 * NPIX + kvn + quad * 8;
        vn[ct][0] = *(const v8s*)(vs);
        vn[ct][1] = *(const v8s*)(vs + 32);
      }
    }
    // p = exp2(s*log2e - 48); 4 consecutive kv per lane -> one b64 LDS write per nt
#pragma unroll
    for (int nt = 0; nt < 4; ++nt) {
      float p0 = exp2f(fmaf(s[nt][0], 1.44269504f, -48.0f));
      float p1 = exp2f(fmaf(s[nt][1], 1.44269504f, -48.0f));
      float p2 = exp2f(fmaf(s[nt][2], 1.44269504f, -48.0f));
      float p3 = exp2f(fmaf(s[nt][3], 1.44269504f, -48.0f));
      v2u pk = {pk_bf16(p0, p1), pk_bf16(p2, p3)};
      *(v2u*)(&Ps[buf][h][ws][lr * 72 + nt * 16 + quad * 4]) = pk;
    }
    __syncthreads();   // P tiles of this half ready
    // O^T += V * P^T for the 4 q-tiles of own half, own 64-ch slice
#pragma unroll
    for (int qt = 0; qt < 4; ++qt) {
      v8s p0 = *(const v8s*)(&Ps[buf][h][qt][lr * 72 + quad * 8]);
      v8s p1 = *(const v8s*)(&Ps[buf][h][qt][lr * 72 + 32 + quad * 8]);
      if (qt == ws) {
        lacc = __builtin_amdgcn_mfma_f32_16x16x32_bf16(ones, p0, lacc, 0, 0, 0);
        lacc = __builtin_amdgcn_mfma_f32_16x16x32_bf16(ones, p1, lacc, 0, 0, 0);
      }
#pragma unroll
      for (int ct = 0; ct < 4; ++ct) {
        acc[qt][ct] = __builtin_amdgcn_mfma_f32_16x16x32_bf16(vf[ct][0], p0, acc[qt][ct], 0, 0, 0);
        acc[qt][ct] = __builtin_amdgcn_mfma_f32_16x16x32_bf16(vf[ct][1], p1, acc[qt][ct], 0, 0, 0);
      }
    }
#pragma unroll
    for (int nt = 0; nt < 4; ++nt) kf[nt] = kn[nt];
#pragma unroll
    for (int ct = 0; ct < 4; ++ct) { vf[ct][0] = vn[ct][0]; vf[ct][1] = vn[ct][1]; }
  }

  // ---- combine halves in LDS (no extra HBM traffic) ----
  __syncthreads();                       // drain last PV reads before Ps reuse
  if (quad == 0) Ls[h][ws * 16 + lr] = lacc[0];
  float* scr = (float*)Ps;               // 36864 B >= 32768 B needed per phase
  if (h == 1) {
#pragma unroll
    for (int qt = 0; qt < 2; ++qt)
#pragma unroll
      for (int ct = 0; ct < 4; ++ct)
        *(v4f*)&scr[((ws * 2 + qt) * 4 + ct) * 256 + lane * 4] = acc[qt][ct];
  }
  __syncthreads();
  float linv[4];
  if (h == 0) {
#pragma unroll
    for (int qt = 0; qt < 2; ++qt)
#pragma unroll
      for (int ct = 0; ct < 4; ++ct) {
        v4f o = *(const v4f*)&scr[((ws * 2 + qt) * 4 + ct) * 256 + lane * 4];
        acc[qt][ct] += o;
      }
#pragma unroll
    for (int qt = 0; qt < 4; ++qt)
      linv[qt] = 1.0f / (Ls[0][qt * 16 + lr] + Ls[1][qt * 16 + lr]);
  }
  __syncthreads();
  if (h == 1) {
#pragma unroll
    for (int qt = 2; qt < 4; ++qt)
#pragma unroll
      for (int ct = 0; ct < 4; ++ct)
        *(v4f*)&scr[((ws * 2 + qt - 2) * 4 + ct) * 256 + lane * 4] = acc[qt][ct];
  }
  __syncthreads();
  if (h == 0) {
#pragma unroll
    for (int qt = 2; qt < 4; ++qt)
#pragma unroll
      for (int ct = 0; ct < 4; ++ct) {
        v4f o = *(const v4f*)&scr[((ws * 2 + qt - 2) * 4 + ct) * 256 + lane * 4];
        acc[qt][ct] += o;
      }
    float* op = out + ((size_t)b * NC + ws * 64) * NPIX + q0;
#pragma unroll
    for (int ct = 0; ct < 4; ++ct)
#pragma unroll
      for (int r = 0; r < 4; ++r) {
        float* orow = op + (size_t)(ct * 16 + quad * 4 + r) * NPIX;
#pragma unroll
        for (int qt = 0; qt < 4; ++qt)
          orow[qt * 16 + lr] = acc[qt][ct][r] * linv[qt];
      }
  }
}

extern "C" void kernel_launch(void* const* d_in, const int* in_sizes, int n_in,
                              void* d_out, int out_size, void* d_ws, size_t ws_size,
                              hipStream_t stream) {
  const float* x  = (const float*)d_in[0];
  const float* y  = (const float*)d_in[1];
  const float* Wq = (const float*)d_in[2];
  const float* bq = (const float*)d_in[3];
  const float* Wk = (const float*)d_in[4];
  const float* bk = (const float*)d_in[5];
  const float* Wv = (const float*)d_in[6];
  const float* bv = (const float*)d_in[7];
  float* out = (float*)d_out;

  // ws: Qb 2MB | Kb 2MB | Vt 16MB | Whq/Whk/Whv 160KB  ~= 20.3MB
  u16* Qb  = (u16*)d_ws;
  u16* Kb  = Qb + (size_t)NB * NPIX * DQK;
  u16* Vt  = Kb + (size_t)NB * NPIX * DQK;
  u16* Whq = Vt + (size_t)NB * NC * NPIX;
  u16* Whk = Whq + 32 * 256;
  u16* Whv = Whk + 32 * 256;

  hipLaunchKernelGGL(convert_w, dim3(320), dim3(256), 0, stream, Wq, Wk, Wv, Whq, Whk, Whv);
  hipLaunchKernelGGL(proj_mfma, dim3(512), dim3(256), 0, stream,
                     x, y, Whq, bq, Whk, bk, Whv, bv, Qb, Kb, Vt);
  hipLaunchKernelGGL(attn_kernel, dim3(512), dim3(512), 0, stream, Qb, Kb, Vt, out);
}

// Round 6
// 325.288 us; speedup vs baseline: 2.2538x; 2.2538x over previous
//
#include <hip/hip_runtime.h>

typedef unsigned short u16;
typedef _Float16 f16;
typedef __attribute__((ext_vector_type(8))) short v8s;
typedef __attribute__((ext_vector_type(4))) short v4s;
typedef __attribute__((ext_vector_type(8))) f16   v8h;
typedef __attribute__((ext_vector_type(4))) float v4f;
typedef __attribute__((ext_vector_type(2))) unsigned v2u;

#define NB   8
#define NC   256
#define DQK  32
#define NPIX 4096

__device__ __forceinline__ u16 f2bf(float f) {
  unsigned u = __builtin_bit_cast(unsigned, f);
  u += 0x7FFFu + ((u >> 16) & 1u);   // RNE
  return (u16)(u >> 16);
}
__device__ __forceinline__ u16 f2h(float f) {
  return __builtin_bit_cast(u16, (f16)f);   // v_cvt_f16_f32, RNE
}
__device__ __forceinline__ unsigned pk_bf16(float a, float b) {  // lo=a, hi=b
#if defined(__gfx950__)
  unsigned r;
  asm("v_cvt_pk_bf16_f32 %0, %1, %2" : "=v"(r) : "v"(a), "v"(b));
  return r;
#else
  return (unsigned)f2bf(a) | ((unsigned)f2bf(b) << 16);
#endif
}

// ---- W -> fp16 ([o][c] row-major, elementwise) ----
__global__ __launch_bounds__(256)
void convert_w(const float* __restrict__ Wq, const float* __restrict__ Wk,
               const float* __restrict__ Wv,
               u16* __restrict__ Whq, u16* __restrict__ Whk, u16* __restrict__ Whv) {
  int i = blockIdx.x * 256 + threadIdx.x;   // 0..81919
  if (i < 8192)       Whq[i]         = f2h(Wq[i]);
  else if (i < 16384) Whk[i - 8192]  = f2h(Wk[i - 8192]);
  else                Whv[i - 16384] = f2h(Wv[i - 16384]);
}

// ---- Projections (Q,K,V) with fused in-LDS transpose of x/y ----
// blockIdx.y splits work: part0 = stage x+y, Q, K, V tiles 0..5;
//                         part1 = stage y,      V tiles 6..15.
__global__ __launch_bounds__(256)
void proj_mfma(const float* __restrict__ x, const float* __restrict__ y,
               const u16* __restrict__ Whq, const float* __restrict__ bq,
               const u16* __restrict__ Whk, const float* __restrict__ bk,
               const u16* __restrict__ Whv, const float* __restrict__ bv,
               u16* __restrict__ Qb, u16* __restrict__ Kb, u16* __restrict__ Vt) {
  __shared__ __attribute__((aligned(16))) unsigned Ts[64][130];   // 33280 B
  const int tid = threadIdx.x, w = tid >> 6, lane = tid & 63;
  const int lr = lane & 15, quad = lane >> 4;
  const int part = blockIdx.y;
  const int b  = blockIdx.x & 7;                 // XCD-affine batch
  const int n0 = (blockIdx.x >> 3) * 64;
  const int g  = tid & 3, nl = tid >> 2;
  const size_t base_b = (size_t)b << 20;

  v8h xb[8], yb[8];
  if (part == 0) {   // stage + fragment x
    const float* s = x + base_b + n0 + nl;
#pragma unroll 4
    for (int i = 0; i < 32; ++i) {
      int c = 2 * g + 8 * i;
      float f0 = s[(size_t)c << 12];
      float f1 = s[(size_t)(c + 1) << 12];
      Ts[nl][g + 4 * i] = (unsigned)f2h(f0) | ((unsigned)f2h(f1) << 16);
    }
    __syncthreads();
    const u16* row = (const u16*)&Ts[w * 16 + lr][0];
#pragma unroll
    for (int t = 0; t < 8; ++t) xb[t] = *(const v8h*)(row + quad * 8 + 32 * t);
    __syncthreads();
  }
  {   // stage + fragment y
    const float* s = y + base_b + n0 + nl;
#pragma unroll 4
    for (int i = 0; i < 32; ++i) {
      int c = 2 * g + 8 * i;
      float f0 = s[(size_t)c << 12];
      float f1 = s[(size_t)(c + 1) << 12];
      Ts[nl][g + 4 * i] = (unsigned)f2h(f0) | ((unsigned)f2h(f1) << 16);
    }
    __syncthreads();
    const u16* row = (const u16*)&Ts[w * 16 + lr][0];
#pragma unroll
    for (int t = 0; t < 8; ++t) yb[t] = *(const v8h*)(row + quad * 8 + 32 * t);
  }

  const int n = n0 + w * 16 + lr;
  const size_t bn = ((size_t)b << 12) + n;

  if (part == 0) {   // Q and K (2 o-tiles each), fp16 out, pixel-major [n][32]
#pragma unroll
    for (int ot = 0; ot < 2; ++ot) {
      v4f aq = {0.f, 0.f, 0.f, 0.f}, ak = {0.f, 0.f, 0.f, 0.f};
#pragma unroll
      for (int t = 0; t < 8; ++t) {
        v8h wq = *(const v8h*)(Whq + (ot * 16 + lr) * 256 + quad * 8 + 32 * t);
        v8h wk = *(const v8h*)(Whk + (ot * 16 + lr) * 256 + quad * 8 + 32 * t);
        aq = __builtin_amdgcn_mfma_f32_16x16x32_f16(wq, xb[t], aq, 0, 0, 0);
        ak = __builtin_amdgcn_mfma_f32_16x16x32_f16(wk, yb[t], ak, 0, 0, 0);
      }
      v4f bqv = *(const v4f*)(bq + ot * 16 + quad * 4);
      v4f bkv = *(const v4f*)(bk + ot * 16 + quad * 4);
      v4s q4, k4;
#pragma unroll
      for (int r = 0; r < 4; ++r) {
        q4[r] = (short)f2h(aq[r] + bqv[r]);
        k4[r] = (short)f2h(ak[r] + bkv[r]);
      }
      *(v4s*)(Qb + bn * DQK + ot * 16 + quad * 4) = q4;
      *(v4s*)(Kb + bn * DQK + ot * 16 + quad * 4) = k4;
    }
  }

  // V o-tiles, software-pipelined W frags -> channel-major bf16 [b][o][n]
  const int vt0 = part ? 6 : 0, vt1 = part ? 16 : 6;
  v8h wvf[8];
#pragma unroll
  for (int t = 0; t < 8; ++t)
    wvf[t] = *(const v8h*)(Whv + (vt0 * 16 + lr) * 256 + quad * 8 + 32 * t);
  for (int vt = vt0; vt < vt1; ++vt) {
    v8h wvn[8];
    if (vt + 1 < vt1) {
#pragma unroll
      for (int t = 0; t < 8; ++t)
        wvn[t] = *(const v8h*)(Whv + ((vt + 1) * 16 + lr) * 256 + quad * 8 + 32 * t);
    }
    v4f av = {0.f, 0.f, 0.f, 0.f};
#pragma unroll
    for (int t = 0; t < 8; ++t)
      av = __builtin_amdgcn_mfma_f32_16x16x32_f16(wvf[t], yb[t], av, 0, 0, 0);
#pragma unroll
    for (int r = 0; r < 4; ++r) {
      int o = vt * 16 + quad * 4 + r;
      Vt[(((size_t)b << 8) + o) * NPIX + n] = f2bf(av[r] + bv[o]);
    }
#pragma unroll
    for (int t = 0; t < 8; ++t) wvf[t] = wvn[t];
  }
}

// ---- Fused attention, kv-split ACROSS blocks (grid 1024 = 4 blocks/CU) ----
// Block: 256 thr, 4 waves, 64 q, kv half h = blockIdx>>9 (2048 kv, 32 iters).
// Writes UNNORMALIZED partial O^T (half0 -> d_out reused as scratch, half1 -> ws)
// plus partial l; combine kernel finishes (O0+O1)/(l0+l1).
__global__ __launch_bounds__(256, 2)
void attn_kernel(const u16* __restrict__ Qb, const u16* __restrict__ Kb,
                 const u16* __restrict__ Vt,
                 float* __restrict__ P0, float* __restrict__ P1,
                 float* __restrict__ Lws) {
  __shared__ __attribute__((aligned(16))) u16 Ps[2][4][16 * 72];  // 18432 B
  __shared__ float Ls[64];

  const int tid  = threadIdx.x;
  const int w    = tid >> 6;
  const int lane = tid & 63;
  const int lr   = lane & 15;
  const int quad = lane >> 4;

  const int b  = blockIdx.x & 7;                 // XCD-affine batch
  const int q0 = ((blockIdx.x >> 3) & 63) << 6;
  const int h  = blockIdx.x >> 9;                // kv half
  const int kvbase = h << 11;

  const u16* Qp = Qb + ((size_t)b * NPIX + q0) * DQK;
  const u16* Kp = Kb + ((size_t)b * NPIX + kvbase) * DQK;
  const u16* Vp = Vt + (size_t)b * NC * NPIX + (size_t)(w * 64 + lr) * NPIX + kvbase;

  v8h q_frag = *(const v8h*)(Qp + (w * 16 + lr) * DQK + quad * 8);

  v8s ones;
#pragma unroll
  for (int j = 0; j < 8; ++j) ones[j] = (short)0x3F80;  // bf16 1.0

  v4f acc[4][4];
#pragma unroll
  for (int qt = 0; qt < 4; ++qt)
#pragma unroll
    for (int ct = 0; ct < 4; ++ct) acc[qt][ct] = (v4f){0.f, 0.f, 0.f, 0.f};
  v4f lacc = (v4f){0.f, 0.f, 0.f, 0.f};

  // prologue loads (it = 0)
  v8h kf[4];
  v8s vf[4][2];
#pragma unroll
  for (int nt = 0; nt < 4; ++nt)
    kf[nt] = *(const v8h*)(Kp + (size_t)(nt * 16 + lr) * DQK + quad * 8);
#pragma unroll
  for (int ct = 0; ct < 4; ++ct) {
    const u16* vs = Vp + (size_t)ct * 16 * NPIX + quad * 8;
    vf[ct][0] = *(const v8s*)(vs);
    vf[ct][1] = *(const v8s*)(vs + 32);
  }

#pragma unroll 2
  for (int it = 0; it < 32; ++it) {
    const int buf = it & 1;
    // S^T = K Q^T : row = kv (quad*4+r), col = q (lr)
    v4f s[4];
#pragma unroll
    for (int nt = 0; nt < 4; ++nt)
      s[nt] = __builtin_amdgcn_mfma_f32_16x16x32_f16(kf[nt], q_frag,
                                                     (v4f){0.f, 0.f, 0.f, 0.f}, 0, 0, 0);
    // prefetch next iteration's K/V
    v8h kn[4];
    v8s vn[4][2];
    if (it < 31) {
      const int kvn = (it + 1) * 64;
#pragma unroll
      for (int nt = 0; nt < 4; ++nt)
        kn[nt] = *(const v8h*)(Kp + (size_t)(kvn + nt * 16 + lr) * DQK + quad * 8);
#pragma unroll
      for (int ct = 0; ct < 4; ++ct) {
        const u16* vs = Vp + (size_t)ct * 16 * NPIX + kvn + quad * 8;
        vn[ct][0] = *(const v8s*)(vs);
        vn[ct][1] = *(const v8s*)(vs + 32);
      }
    }
    // p = exp2(s*log2e - 48); 4 consecutive kv per lane -> one b64 LDS write per nt
#pragma unroll
    for (int nt = 0; nt < 4; ++nt) {
      float p0 = exp2f(fmaf(s[nt][0], 1.44269504f, -48.0f));
      float p1 = exp2f(fmaf(s[nt][1], 1.44269504f, -48.0f));
      float p2 = exp2f(fmaf(s[nt][2], 1.44269504f, -48.0f));
      float p3 = exp2f(fmaf(s[nt][3], 1.44269504f, -48.0f));
      v2u pk = {pk_bf16(p0, p1), pk_bf16(p2, p3)};
      *(v2u*)(&Ps[buf][w][lr * 72 + nt * 16 + quad * 4]) = pk;
    }
    __syncthreads();
    // O^T += V * P^T for all 4 q-tiles, own 64-ch slice
#pragma unroll
    for (int qt = 0; qt < 4; ++qt) {
      v8s p0 = *(const v8s*)(&Ps[buf][qt][lr * 72 + quad * 8]);
      v8s p1 = *(const v8s*)(&Ps[buf][qt][lr * 72 + 32 + quad * 8]);
      if (qt == w) {
        lacc = __builtin_amdgcn_mfma_f32_16x16x32_bf16(ones, p0, lacc, 0, 0, 0);
        lacc = __builtin_amdgcn_mfma_f32_16x16x32_bf16(ones, p1, lacc, 0, 0, 0);
      }
#pragma unroll
      for (int ct = 0; ct < 4; ++ct) {
        acc[qt][ct] = __builtin_amdgcn_mfma_f32_16x16x32_bf16(vf[ct][0], p0, acc[qt][ct], 0, 0, 0);
        acc[qt][ct] = __builtin_amdgcn_mfma_f32_16x16x32_bf16(vf[ct][1], p1, acc[qt][ct], 0, 0, 0);
      }
    }
#pragma unroll
    for (int nt = 0; nt < 4; ++nt) kf[nt] = kn[nt];
#pragma unroll
    for (int ct = 0; ct < 4; ++ct) { vf[ct][0] = vn[ct][0]; vf[ct][1] = vn[ct][1]; }
  }

  // ---- epilogue: write UNNORMALIZED partial O^T + partial l ----
  if (quad == 0) Ls[w * 16 + lr] = lacc[0];
  __syncthreads();

  float* Pp = h ? P1 : P0;
  float* op = Pp + ((size_t)b * NC + w * 64) * NPIX + q0;
#pragma unroll
  for (int ct = 0; ct < 4; ++ct)
#pragma unroll
    for (int r = 0; r < 4; ++r) {
      float* orow = op + (size_t)(ct * 16 + quad * 4 + r) * NPIX;
#pragma unroll
      for (int qt = 0; qt < 4; ++qt)
        orow[qt * 16 + lr] = acc[qt][ct][r];
    }
  if (tid < 64) Lws[((size_t)h * NB + b) * NPIX + q0 + tid] = Ls[tid];
}

// ---- combine: out = (P0 + P1) / (l0 + l1), in place over d_out ----
// Covers out_size = 8*256*4096 = 8,388,608 floats: 8192 blocks * 256 thr * 4 floats.
__global__ __launch_bounds__(256)
void combine(float* __restrict__ outP, const float* __restrict__ P1,
             const float* __restrict__ Lws) {
  const size_t i = ((size_t)blockIdx.x * 256 + threadIdx.x) << 2;  // float index
  v4f a = *(const v4f*)(outP + i);
  v4f c = *(const v4f*)(P1 + i);
  const int q    = (int)(i & 4095);
  const int bidx = (int)(i >> 20);
  const float* lb = Lws + ((size_t)bidx << 12) + q;
  v4f l0 = *(const v4f*)lb;
  v4f l1 = *(const v4f*)(lb + (size_t)NB * NPIX);
  v4f o;
#pragma unroll
  for (int k = 0; k < 4; ++k) o[k] = (a[k] + c[k]) * (1.0f / (l0[k] + l1[k]));
  *(v4f*)(outP + i) = o;
}

extern "C" void kernel_launch(void* const* d_in, const int* in_sizes, int n_in,
                              void* d_out, int out_size, void* d_ws, size_t ws_size,
                              hipStream_t stream) {
  const float* x  = (const float*)d_in[0];
  const float* y  = (const float*)d_in[1];
  const float* Wq = (const float*)d_in[2];
  const float* bq = (const float*)d_in[3];
  const float* Wk = (const float*)d_in[4];
  const float* bk = (const float*)d_in[5];
  const float* Wv = (const float*)d_in[6];
  const float* bv = (const float*)d_in[7];
  float* out = (float*)d_out;

  // ws: Qb 2MB | Kb 2MB | Vt 16MB | Whq/Whk/Whv 160KB | P1 32MB | Lws 256KB ~= 52.6MB
  u16* Qb  = (u16*)d_ws;
  u16* Kb  = Qb + (size_t)NB * NPIX * DQK;
  u16* Vt  = Kb + (size_t)NB * NPIX * DQK;
  u16* Whq = Vt + (size_t)NB * NC * NPIX;
  u16* Whk = Whq + 32 * 256;
  u16* Whv = Whk + 32 * 256;
  float* P1  = (float*)(Whv + 256 * 256);
  float* Lws = P1 + (size_t)NB * NC * NPIX;

  hipLaunchKernelGGL(convert_w, dim3(320), dim3(256), 0, stream, Wq, Wk, Wv, Whq, Whk, Whv);
  hipLaunchKernelGGL(proj_mfma, dim3(512, 2), dim3(256), 0, stream,
                     x, y, Whq, bq, Whk, bk, Whv, bv, Qb, Kb, Vt);
  hipLaunchKernelGGL(attn_kernel, dim3(1024), dim3(256), 0, stream,
                     Qb, Kb, Vt, out, P1, Lws);
  hipLaunchKernelGGL(combine, dim3(8192), dim3(256), 0, stream, out, P1, Lws);
}